// Round 13
// baseline (2967.368 us; speedup 1.0000x reference)
//
#include <hip/hip_runtime.h>

#define BB    2      // batches
#define NN    8192   // points per batch
#define CC    64     // extra feature channels
#define NPT   1024   // npoint
#define NT    128    // 64-wide tiles per dim (8192/64)
#define NBLK  16     // fallback: blocks per batch
#define TPB   512    // fallback: threads per block (1 point per thread)

typedef __attribute__((address_space(3))) unsigned int       lds_u32;
typedef __attribute__((address_space(1))) const unsigned int glb_u32;

// monotonic order-preserving key for f32 (handles negatives)
__device__ __forceinline__ unsigned int fkey(float v) {
  unsigned int u = __float_as_uint(v);
  return (u & 0x80000000u) ? ~u : (u | 0x80000000u);
}

// wave64 max-reduce of u32 via DPP (rocPRIM pattern); result broadcast via
// readlane(63). Prefix-max over rows (shr 1/2/4/8) then row_bcast 15/31.
__device__ __forceinline__ unsigned wave_max_u32(unsigned x) {
  int v = (int)x, t;
  t = __builtin_amdgcn_update_dpp(v, v, 0x111, 0xf, 0xf, false);  // row_shr:1
  v = ((unsigned)t > (unsigned)v) ? t : v;
  t = __builtin_amdgcn_update_dpp(v, v, 0x112, 0xf, 0xf, false);  // row_shr:2
  v = ((unsigned)t > (unsigned)v) ? t : v;
  t = __builtin_amdgcn_update_dpp(v, v, 0x114, 0xf, 0xf, false);  // row_shr:4
  v = ((unsigned)t > (unsigned)v) ? t : v;
  t = __builtin_amdgcn_update_dpp(v, v, 0x118, 0xf, 0xf, false);  // row_shr:8
  v = ((unsigned)t > (unsigned)v) ? t : v;
  t = __builtin_amdgcn_update_dpp(v, v, 0x142, 0xa, 0xf, false);  // row_bcast:15
  v = ((unsigned)t > (unsigned)v) ? t : v;
  t = __builtin_amdgcn_update_dpp(v, v, 0x143, 0xc, 0xf, false);  // row_bcast:31
  v = ((unsigned)t > (unsigned)v) ? t : v;
  return (unsigned)__builtin_amdgcn_readlane(v, 63);
}

// ======================= D-path: dist build (per batch) =======================
// D[i][j] = n_i + n_j - 2*dot(A_i,A_j); ascending-k fmaf chains -> D[i][i] == 0
// bit-exactly. 82% of fp32 vector peak (R9) — done.
__global__ __launch_bounds__(256) void dist_kernel(
    const float* __restrict__ Pb,    // (N,3) for this batch
    const float* __restrict__ Fb,    // (C,N) for this batch
    float* __restrict__ Db) {        // (N,N) out
  __shared__ __align__(16) float Ai[67][64];
  __shared__ __align__(16) float Aj[67][64];
  __shared__ float ni_s[64], nj_s[64];
  const int bid = blockIdx.x;
  const int bi  = bid >> 7, bj = bid & (NT - 1);
  const int t   = threadIdx.x;
  const int i0  = bi * 64, j0 = bj * 64;

  for (int idx = t; idx < 67 * 64; idx += 256) {
    const int c = idx >> 6, r = idx & 63;
    float vi, vj;
    if (c < 3) {
      vi = Pb[(size_t)(i0 + r) * 3 + c];
      vj = Pb[(size_t)(j0 + r) * 3 + c];
    } else {
      vi = Fb[(size_t)(c - 3) * NN + i0 + r];
      vj = Fb[(size_t)(c - 3) * NN + j0 + r];
    }
    Ai[c][r] = vi;
    Aj[c][r] = vj;
  }
  __syncthreads();

  if (t < 64) {
    float n = 0.f;
#pragma unroll
    for (int k = 0; k < 67; ++k) n = fmaf(Ai[k][t], Ai[k][t], n);
    ni_s[t] = n;
  } else if (t < 128) {
    const int r = t - 64;
    float n = 0.f;
#pragma unroll
    for (int k = 0; k < 67; ++k) n = fmaf(Aj[k][r], Aj[k][r], n);
    nj_s[r] = n;
  }
  __syncthreads();

  const int tx = t & 15, ty = t >> 4;
  float acc[4][4] = {};
  for (int k = 0; k < 67; ++k) {
    const float4 a = *(const float4*)&Ai[k][ty * 4];
    const float4 v = *(const float4*)&Aj[k][tx * 4];
    acc[0][0] = fmaf(a.x, v.x, acc[0][0]); acc[0][1] = fmaf(a.x, v.y, acc[0][1]);
    acc[0][2] = fmaf(a.x, v.z, acc[0][2]); acc[0][3] = fmaf(a.x, v.w, acc[0][3]);
    acc[1][0] = fmaf(a.y, v.x, acc[1][0]); acc[1][1] = fmaf(a.y, v.y, acc[1][1]);
    acc[1][2] = fmaf(a.y, v.z, acc[1][2]); acc[1][3] = fmaf(a.y, v.w, acc[1][3]);
    acc[2][0] = fmaf(a.z, v.x, acc[2][0]); acc[2][1] = fmaf(a.z, v.y, acc[2][1]);
    acc[2][2] = fmaf(a.z, v.z, acc[2][2]); acc[2][3] = fmaf(a.z, v.w, acc[2][3]);
    acc[3][0] = fmaf(a.w, v.x, acc[3][0]); acc[3][1] = fmaf(a.w, v.y, acc[3][1]);
    acc[3][2] = fmaf(a.w, v.z, acc[3][2]); acc[3][3] = fmaf(a.w, v.w, acc[3][3]);
  }

  const float4 nj4 = *(const float4*)&nj_s[tx * 4];
#pragma unroll
  for (int r = 0; r < 4; ++r) {
    const float nir = ni_s[ty * 4 + r];
    float4 w;
    w.x = (nir + nj4.x) - 2.0f * acc[r][0];
    w.y = (nir + nj4.y) - 2.0f * acc[r][1];
    w.z = (nir + nj4.z) - 2.0f * acc[r][2];
    w.w = (nir + nj4.w) - 2.0f * acc[r][3];
    *(float4*)&Db[(size_t)(i0 + ty * 4 + r) * NN + j0 + tx * 4] = w;
  }
}

// ======================= D-path: serial scan (speculative execution) =========
// One block (512 thr, 8 waves, 1 CU) per batch; block-local sync only.
// vs R12: (1) spec-fmin reordered BEFORE the DMA issue, so conservative vmcnt
// waits drain only the ~1-step-old DMA, never the fresh one; (2) each wave
// DMAs exactly the row slices IT consumes (256w + 2048k) -> correctness needs
// only the wave's own vmcnt; (3) raw s_barrier + lgkmcnt(0) (no vmcnt(0)
// drain) so DMA flight spans barriers. Hit commit is bit-exact fmin(m, row).

// producer-side fence + barrier + consumer-side fence (no vmem drain)
#define BARRIER_NOVM()                                         \
  asm volatile("s_waitcnt lgkmcnt(0)" ::: "memory");           \
  __builtin_amdgcn_s_barrier();                                \
  asm volatile("" ::: "memory")

#define SCAN_STEP(BUFC, PREDC, BUFN, s)                                        \
  {                                                                            \
    if (far == PREDC) {              /* hit: commit speculative state */       \
      m0 = p0; m1 = p1; m2 = p2; m3 = p3;                                      \
    } else {                         /* miss: demand global load */            \
      const float4* r4_ = (const float4*)(Db + (size_t)far * NN);              \
      const float4 v0_ = r4_[tid],        v1_ = r4_[tid + 512];                \
      const float4 v2_ = r4_[tid + 1024], v3_ = r4_[tid + 1536];               \
      m0.x = fminf(m0.x, v0_.x); m0.y = fminf(m0.y, v0_.y);                    \
      m0.z = fminf(m0.z, v0_.z); m0.w = fminf(m0.w, v0_.w);                    \
      m1.x = fminf(m1.x, v1_.x); m1.y = fminf(m1.y, v1_.y);                    \
      m1.z = fminf(m1.z, v1_.z); m1.w = fminf(m1.w, v1_.w);                    \
      m2.x = fminf(m2.x, v2_.x); m2.y = fminf(m2.y, v2_.y);                    \
      m2.z = fminf(m2.z, v2_.z); m2.w = fminf(m2.w, v2_.w);                    \
      m3.x = fminf(m3.x, v3_.x); m3.y = fminf(m3.y, v3_.y);                    \
      m3.z = fminf(m3.z, v3_.z); m3.w = fminf(m3.w, v3_.w);                    \
    }                                                                          \
    /* thread max via fmax tree (short dep chain; v_max3-friendly) */          \
    const float ta_ = fmaxf(fmaxf(fmaxf(m0.x, m0.y), fmaxf(m0.z, m0.w)),       \
                            fmaxf(fmaxf(m1.x, m1.y), fmaxf(m1.z, m1.w)));      \
    const float tb_ = fmaxf(fmaxf(fmaxf(m2.x, m2.y), fmaxf(m2.z, m2.w)),       \
                            fmaxf(fmaxf(m3.x, m3.y), fmaxf(m3.z, m3.w)));      \
    const float tm_ = fmaxf(ta_, tb_);                                         \
    /* lowest-j recovery (descending j; runs parallel to DPP chain) */         \
    const int j0_ = tid * 4;                                                   \
    int bj = 0;                                                                \
    bj = (m3.w == tm_) ? j0_ + 6147 : bj; bj = (m3.z == tm_) ? j0_ + 6146 : bj;\
    bj = (m3.y == tm_) ? j0_ + 6145 : bj; bj = (m3.x == tm_) ? j0_ + 6144 : bj;\
    bj = (m2.w == tm_) ? j0_ + 4099 : bj; bj = (m2.z == tm_) ? j0_ + 4098 : bj;\
    bj = (m2.y == tm_) ? j0_ + 4097 : bj; bj = (m2.x == tm_) ? j0_ + 4096 : bj;\
    bj = (m1.w == tm_) ? j0_ + 2051 : bj; bj = (m1.z == tm_) ? j0_ + 2050 : bj;\
    bj = (m1.y == tm_) ? j0_ + 2049 : bj; bj = (m1.x == tm_) ? j0_ + 2048 : bj;\
    bj = (m0.w == tm_) ? j0_ + 3 : bj;    bj = (m0.z == tm_) ? j0_ + 2 : bj;   \
    bj = (m0.y == tm_) ? j0_ + 1 : bj;    bj = (m0.x == tm_) ? j0_ : bj;       \
    const unsigned fk_   = fkey(tm_);                                          \
    const unsigned wmax_ = wave_max_u32(fk_);                                  \
    const unsigned cand_ = (fk_ == wmax_) ? (8191u - (unsigned)bj) : 0u;       \
    const unsigned wtie_ = wave_max_u32(cand_);                                \
    if (lane == 0)                                                             \
      wred[(s) & 1][wid] = ((unsigned long long)wmax_ << 32) | wtie_;          \
    BARRIER_NOVM();   /* DMA flight NOT drained (wave-self slices) */          \
    const unsigned long long* W_ = wred[(s) & 1];                              \
    const unsigned long long g0_=W_[0], g1_=W_[1], g2_=W_[2], g3_=W_[3],       \
                             g4_=W_[4], g5_=W_[5], g6_=W_[6], g7_=W_[7];       \
    unsigned long long h0_ = g0_>g1_?g0_:g1_, h1_ = g2_>g3_?g2_:g3_;           \
    unsigned long long h2_ = g4_>g5_?g4_:g5_, h3_ = g6_>g7_?g6_:g7_;           \
    unsigned long long q0_ = h0_>h1_?h0_:h1_, q1_ = h2_>h3_?h2_:h3_;           \
    const unsigned long long win_ = q0_>q1_?q0_:q1_;                           \
    far = 8191 - (int)(win_ & 0x1FFFu);                                        \
    if (tid == 0) ob[s] = far;                                                 \
    /* runner-up = prediction for far_{s+2} (keys distinct across waves) */    \
    unsigned long long e0_ = g0_==win_?0ull:g0_, e1_ = g1_==win_?0ull:g1_;     \
    unsigned long long e2_ = g2_==win_?0ull:g2_, e3_ = g3_==win_?0ull:g3_;     \
    unsigned long long e4_ = g4_==win_?0ull:g4_, e5_ = g5_==win_?0ull:g5_;     \
    unsigned long long e6_ = g6_==win_?0ull:g6_, e7_ = g7_==win_?0ull:g7_;     \
    e0_ = e0_>e1_?e0_:e1_; e2_ = e2_>e3_?e2_:e3_;                              \
    e4_ = e4_>e5_?e4_:e5_; e6_ = e6_>e7_?e6_:e7_;                              \
    e0_ = e0_>e2_?e0_:e2_; e4_ = e4_>e6_?e4_:e6_;                              \
    const unsigned long long sec_ = e0_>e4_?e0_:e4_;                           \
    const int run_ = 8191 - (int)(sec_ & 0x1FFFu);                             \
    /* speculative fmin for step s+1 from BUFN (wave-self slices; DMA'd at    \
       step s-1 -> ~1 full step of flight; conservative vmcnt here drains     \
       only old DMAs because the new one is NOT yet issued) */                 \
    {                                                                          \
      const float4* l4_ = (const float4*)(BUFN);                               \
      const float4 q0_ = l4_[tid],        q1_ = l4_[tid + 512];                \
      const float4 q2_ = l4_[tid + 1024], q3_ = l4_[tid + 1536];               \
      p0.x = fminf(m0.x, q0_.x); p0.y = fminf(m0.y, q0_.y);                    \
      p0.z = fminf(m0.z, q0_.z); p0.w = fminf(m0.w, q0_.w);                    \
      p1.x = fminf(m1.x, q1_.x); p1.y = fminf(m1.y, q1_.y);                    \
      p1.z = fminf(m1.z, q1_.z); p1.w = fminf(m1.w, q1_.w);                    \
      p2.x = fminf(m2.x, q2_.x); p2.y = fminf(m2.y, q2_.y);                    \
      p2.z = fminf(m2.z, q2_.z); p2.w = fminf(m2.w, q2_.w);                    \
      p3.x = fminf(m3.x, q3_.x); p3.y = fminf(m3.y, q3_.y);                    \
      p3.z = fminf(m3.z, q3_.z); p3.w = fminf(m3.w, q3_.w);                    \
    }                                                                          \
    /* async DMA row[run_] -> BUFC, wave-self slices (256*wid + 2048k);        \
       spec-consumed at end of s+1 by the SAME wave only */                    \
    {                                                                          \
      const float* gr_ = Db + (size_t)run_ * NN + (wid << 8) + (lane << 2);    \
      float* lr_ = (BUFC) + (wid << 8);                                        \
      __builtin_amdgcn_global_load_lds((glb_u32*)gr_, (lds_u32*)lr_, 16, 0, 0);\
      __builtin_amdgcn_global_load_lds((glb_u32*)(gr_ + 2048),                 \
                                       (lds_u32*)(lr_ + 2048), 16, 0, 0);      \
      __builtin_amdgcn_global_load_lds((glb_u32*)(gr_ + 4096),                 \
                                       (lds_u32*)(lr_ + 4096), 16, 0, 0);      \
      __builtin_amdgcn_global_load_lds((glb_u32*)(gr_ + 6144),                 \
                                       (lds_u32*)(lr_ + 6144), 16, 0, 0);      \
      PREDC = run_;                                                            \
    }                                                                          \
  }

__global__ __attribute__((amdgpu_waves_per_eu(1, 2))) __launch_bounds__(512)
void scan_kernel(const float* __restrict__ D, unsigned long long dstride,
                 int* __restrict__ out, int ostride) {
  const int b = blockIdx.x;
  const float* Db = D + (size_t)b * dstride;
  int* ob = out + (size_t)b * ostride;
  const int tid = threadIdx.x, lane = tid & 63, wid = tid >> 6;  // 8 waves
  __shared__ unsigned long long wred[2][8];
  __shared__ __align__(16) float bufA[NN], bufB[NN];   // 2 x 32 KiB ping-pong

  float4 m0 = make_float4(3.0e38f, 3.0e38f, 3.0e38f, 3.0e38f);
  float4 m1 = m0, m2 = m0, m3 = m0;
  float4 p0 = m0, p1 = m0, p2 = m0, p3 = m0;           // speculative state
  int far = 0, predA = -1, predB = -1;

  if (tid == 0) ob[0] = 0;

  int s = 1;
#pragma unroll 1
  for (int pair = 0; pair < (NPT - 2) / 2; ++pair) {   // s = 1..1022
    SCAN_STEP(bufA, predA, bufB, s)
    ++s;
    SCAN_STEP(bufB, predB, bufA, s)
    ++s;
  }
  SCAN_STEP(bufA, predA, bufB, s)                      // s = 1023
}

// ======================= fallback path (small ws; kept for safety) =======================

#define R64(M) \
  M(0) M(1) M(2) M(3) M(4) M(5) M(6) M(7) \
  M(8) M(9) M(10) M(11) M(12) M(13) M(14) M(15) \
  M(16) M(17) M(18) M(19) M(20) M(21) M(22) M(23) \
  M(24) M(25) M(26) M(27) M(28) M(29) M(30) M(31) \
  M(32) M(33) M(34) M(35) M(36) M(37) M(38) M(39) \
  M(40) M(41) M(42) M(43) M(44) M(45) M(46) M(47) \
  M(48) M(49) M(50) M(51) M(52) M(53) M(54) M(55) \
  M(56) M(57) M(58) M(59) M(60) M(61) M(62) M(63)

__global__ __attribute__((amdgpu_waves_per_eu(1, 2))) __launch_bounds__(TPB)
void fps_fallback(const float* __restrict__ pts, const float* __restrict__ feat,
                  int* __restrict__ out, unsigned long long* __restrict__ slots) {
  const int blk  = blockIdx.x & (NBLK - 1);
  const int b    = blockIdx.x >> 4;
  const int tid  = threadIdx.x;
  const int lane = tid & 63;
  const int p    = blk * TPB + tid;

  const float* Pp = pts  + (size_t)b * NN * 3 + (size_t)p * 3;
  const float* Fp = feat + (size_t)b * CC * NN + p;

  float fx = Pp[0], fy = Pp[1], fz = Pp[2];
#define DCF(i) float fc##i = Fp[(i) * NN];
  R64(DCF)
#undef DCF
  asm volatile("" : "+v"(fx), "+v"(fy), "+v"(fz));
#define PIN(i) asm volatile("" : "+v"(fc##i));
  R64(PIN)
#undef PIN

  float nrm = 0.f;
  nrm += fx * fx; nrm += fy * fy; nrm += fz * fz;
#define NR(i) nrm += fc##i * fc##i;
  R64(NR)
#undef NR

  __shared__ unsigned long long wred[TPB / 64];
  __shared__ int far_sh;

  if (blk == 0 && tid == 0) out[b * NPT] = 0;

  float mind = 3.0e38f;
  int far = 0;

  for (int s = 1; s < NPT; ++s) {
    const int fu = __builtin_amdgcn_readfirstlane(far);
    const float* Pq = pts  + (size_t)b * NN * 3 + (size_t)fu * 3;
    const float* Fq = feat + (size_t)b * CC * NN + fu;
    const float gx = Pq[0], gy = Pq[1], gz = Pq[2];
#define GL(i) const float gc##i = Fq[(i) * NN];
    R64(GL)
#undef GL
    float nf = 0.f, dot = 0.f;
    nf += gx * gx; nf += gy * gy; nf += gz * gz;
#define NF(i) nf += gc##i * gc##i;
    R64(NF)
#undef NF
    dot += fx * gx; dot += fy * gy; dot += fz * gz;
#define DT(i) dot += fc##i * gc##i;
    R64(DT)
#undef DT
    const float d = (nf + nrm) - 2.0f * dot;
    mind = fminf(mind, d);

    unsigned long long key =
        ((unsigned long long)fkey(mind) << 13) | (unsigned int)(8191 - p);
#pragma unroll
    for (int off = 1; off < 64; off <<= 1) {
      unsigned long long o = __shfl_xor(key, off);
      key = key > o ? key : o;
    }
    if (lane == 0) wred[tid >> 6] = key;
    __syncthreads();

    if (tid < 64) {
      unsigned long long bk = wred[0];
#pragma unroll
      for (int w = 1; w < TPB / 64; ++w) bk = bk > wred[w] ? bk : wred[w];
      unsigned long long* sb = slots + ((size_t)(s & 1) * BB + b) * NBLK;
      if (tid == 0) {
        bk |= ((unsigned long long)s << 45);
        __hip_atomic_store(&sb[blk], bk, __ATOMIC_RELAXED, __HIP_MEMORY_SCOPE_AGENT);
      }
      unsigned long long v = 0;
      for (;;) {
        if (tid < NBLK)
          v = __hip_atomic_load(&sb[tid], __ATOMIC_RELAXED, __HIP_MEMORY_SCOPE_AGENT);
        const bool ok = (tid < NBLK) ? ((v >> 45) == (unsigned long long)s) : true;
        if (__all(ok)) break;
        __builtin_amdgcn_s_sleep(1);
      }
#pragma unroll
      for (int off = 8; off; off >>= 1) {
        unsigned long long o = __shfl_xor(v, off);
        v = v > o ? v : o;
      }
      if (tid == 0) far_sh = 8191 - (int)(v & 0x1FFFu);
    }
    __syncthreads();
    far = far_sh;
    if (blk == 0 && tid == 0) out[b * NPT + s] = far;
  }
}

// ======================= host =======================

extern "C" void kernel_launch(void* const* d_in, const int* in_sizes, int n_in,
                              void* d_out, int out_size, void* d_ws, size_t ws_size,
                              hipStream_t stream) {
  const float* pts  = (const float*)d_in[0];
  const float* feat = (const float*)d_in[1];
  int* out = (int*)d_out;

  const size_t oneD = (size_t)NN * NN * sizeof(float);   // 256 MiB
  if (ws_size >= 2 * oneD) {
    float* D = (float*)d_ws;
    for (int b = 0; b < BB; ++b)
      dist_kernel<<<NT * NT, 256, 0, stream>>>(
          pts + (size_t)b * NN * 3, feat + (size_t)b * CC * NN, D + (size_t)b * NN * NN);
    scan_kernel<<<BB, 512, 0, stream>>>(D, (unsigned long long)NN * NN, out, NPT);
  } else if (ws_size >= oneD) {
    float* D = (float*)d_ws;
    for (int b = 0; b < BB; ++b) {
      dist_kernel<<<NT * NT, 256, 0, stream>>>(
          pts + (size_t)b * NN * 3, feat + (size_t)b * CC * NN, D);
      scan_kernel<<<1, 512, 0, stream>>>(D, 0, out + (size_t)b * NPT, 0);
    }
  } else {
    unsigned long long* slots = (unsigned long long*)d_ws; // [2][BB][NBLK] = 512 B
    hipMemsetAsync(d_ws, 0, 2 * BB * NBLK * sizeof(unsigned long long), stream);
    void* args[] = {(void*)&pts, (void*)&feat, (void*)&out, (void*)&slots};
    dim3 grid(BB * NBLK), block(TPB);
    hipLaunchCooperativeKernel((void*)fps_fallback, grid, block, args, 0, stream);
  }
}

// Round 14
// 2751.845 us; speedup vs baseline: 1.0783x; 1.0783x over previous
//
#include <hip/hip_runtime.h>

#define BB    2      // batches
#define NN    8192   // points per batch
#define CC    64     // extra feature channels
#define NPT   1024   // npoint
#define NT    128    // 64-wide tiles per dim (8192/64)
#define NBLK  16     // fallback: blocks per batch
#define TPB   512    // fallback: threads per block (1 point per thread)

// monotonic order-preserving key for f32 (handles negatives)
__device__ __forceinline__ unsigned int fkey(float v) {
  unsigned int u = __float_as_uint(v);
  return (u & 0x80000000u) ? ~u : (u | 0x80000000u);
}

// wave64 max-reduce of u32 via DPP (rocPRIM pattern); uniform via readlane(63).
__device__ __forceinline__ unsigned wave_max_u32(unsigned x) {
  int v = (int)x, t;
  t = __builtin_amdgcn_update_dpp(v, v, 0x111, 0xf, 0xf, false);  // row_shr:1
  v = ((unsigned)t > (unsigned)v) ? t : v;
  t = __builtin_amdgcn_update_dpp(v, v, 0x112, 0xf, 0xf, false);  // row_shr:2
  v = ((unsigned)t > (unsigned)v) ? t : v;
  t = __builtin_amdgcn_update_dpp(v, v, 0x114, 0xf, 0xf, false);  // row_shr:4
  v = ((unsigned)t > (unsigned)v) ? t : v;
  t = __builtin_amdgcn_update_dpp(v, v, 0x118, 0xf, 0xf, false);  // row_shr:8
  v = ((unsigned)t > (unsigned)v) ? t : v;
  t = __builtin_amdgcn_update_dpp(v, v, 0x142, 0xa, 0xf, false);  // row_bcast:15
  v = ((unsigned)t > (unsigned)v) ? t : v;
  t = __builtin_amdgcn_update_dpp(v, v, 0x143, 0xc, 0xf, false);  // row_bcast:31
  v = ((unsigned)t > (unsigned)v) ? t : v;
  return (unsigned)__builtin_amdgcn_readlane(v, 63);
}

// ======================= D-path: dist build (per batch) =======================
// D[i][j] = n_i + n_j - 2*dot(A_i,A_j); ascending-k fmaf chains -> D[i][i] == 0
// bit-exactly. 82% of fp32 vector peak (R9) — done.
__global__ __launch_bounds__(256) void dist_kernel(
    const float* __restrict__ Pb,    // (N,3) for this batch
    const float* __restrict__ Fb,    // (C,N) for this batch
    float* __restrict__ Db) {        // (N,N) out
  __shared__ __align__(16) float Ai[67][64];
  __shared__ __align__(16) float Aj[67][64];
  __shared__ float ni_s[64], nj_s[64];
  const int bid = blockIdx.x;
  const int bi  = bid >> 7, bj = bid & (NT - 1);
  const int t   = threadIdx.x;
  const int i0  = bi * 64, j0 = bj * 64;

  for (int idx = t; idx < 67 * 64; idx += 256) {
    const int c = idx >> 6, r = idx & 63;
    float vi, vj;
    if (c < 3) {
      vi = Pb[(size_t)(i0 + r) * 3 + c];
      vj = Pb[(size_t)(j0 + r) * 3 + c];
    } else {
      vi = Fb[(size_t)(c - 3) * NN + i0 + r];
      vj = Fb[(size_t)(c - 3) * NN + j0 + r];
    }
    Ai[c][r] = vi;
    Aj[c][r] = vj;
  }
  __syncthreads();

  if (t < 64) {
    float n = 0.f;
#pragma unroll
    for (int k = 0; k < 67; ++k) n = fmaf(Ai[k][t], Ai[k][t], n);
    ni_s[t] = n;
  } else if (t < 128) {
    const int r = t - 64;
    float n = 0.f;
#pragma unroll
    for (int k = 0; k < 67; ++k) n = fmaf(Aj[k][r], Aj[k][r], n);
    nj_s[r] = n;
  }
  __syncthreads();

  const int tx = t & 15, ty = t >> 4;
  float acc[4][4] = {};
  for (int k = 0; k < 67; ++k) {
    const float4 a = *(const float4*)&Ai[k][ty * 4];
    const float4 v = *(const float4*)&Aj[k][tx * 4];
    acc[0][0] = fmaf(a.x, v.x, acc[0][0]); acc[0][1] = fmaf(a.x, v.y, acc[0][1]);
    acc[0][2] = fmaf(a.x, v.z, acc[0][2]); acc[0][3] = fmaf(a.x, v.w, acc[0][3]);
    acc[1][0] = fmaf(a.y, v.x, acc[1][0]); acc[1][1] = fmaf(a.y, v.y, acc[1][1]);
    acc[1][2] = fmaf(a.y, v.z, acc[1][2]); acc[1][3] = fmaf(a.y, v.w, acc[1][3]);
    acc[2][0] = fmaf(a.z, v.x, acc[2][0]); acc[2][1] = fmaf(a.z, v.y, acc[2][1]);
    acc[2][2] = fmaf(a.z, v.z, acc[2][2]); acc[2][3] = fmaf(a.z, v.w, acc[2][3]);
    acc[3][0] = fmaf(a.w, v.x, acc[3][0]); acc[3][1] = fmaf(a.w, v.y, acc[3][1]);
    acc[3][2] = fmaf(a.w, v.z, acc[3][2]); acc[3][3] = fmaf(a.w, v.w, acc[3][3]);
  }

  const float4 nj4 = *(const float4*)&nj_s[tx * 4];
#pragma unroll
  for (int r = 0; r < 4; ++r) {
    const float nir = ni_s[ty * 4 + r];
    float4 w;
    w.x = (nir + nj4.x) - 2.0f * acc[r][0];
    w.y = (nir + nj4.y) - 2.0f * acc[r][1];
    w.z = (nir + nj4.z) - 2.0f * acc[r][2];
    w.w = (nir + nj4.w) - 2.0f * acc[r][3];
    *(float4*)&Db[(size_t)(i0 + ty * 4 + r) * NN + j0 + tx * 4] = w;
  }
}

// ======================= D-path: serial scan (R9 structure, lean VALU) =======
// One block (512 thr, 8 waves, 1 CU) per batch; block-local sync only.
// Thread tid owns j in [tid*16, tid*16+16) -> tie-break is lane-monotone:
// wave winner = lowest lane with fk==wmax (ballot+ffs), no second DPP chain.
// fmax tree (depth 4) + descending select ladder for lowest-k. 3-slot rotating
// LDS cell + single barrier per step (R9-proven race-free).
__global__ __launch_bounds__(512) void scan_kernel(
    const float* __restrict__ D, unsigned long long dstride,
    int* __restrict__ out, int ostride) {
  const int b = blockIdx.x;
  const float* Db = D + (size_t)b * dstride;
  int* ob = out + (size_t)b * ostride;
  const int tid = threadIdx.x, lane = tid & 63;
  __shared__ unsigned long long slot[3];
  if (tid < 3) slot[tid] = 0ull;
  __syncthreads();

  float4 m0 = make_float4(3.0e38f, 3.0e38f, 3.0e38f, 3.0e38f);
  float4 m1 = m0, m2 = m0, m3 = m0;

  if (tid == 0) ob[0] = 0;
  int far = 0;

  for (int s = 1; s < NPT; ++s) {
    // demand load: 16 contiguous floats per thread (4 x float4)
    const float4* row4 = (const float4*)(Db + (size_t)far * NN) + (tid << 2);
    const float4 v0 = row4[0], v1 = row4[1], v2 = row4[2], v3 = row4[3];
    m0.x = fminf(m0.x, v0.x); m0.y = fminf(m0.y, v0.y);
    m0.z = fminf(m0.z, v0.z); m0.w = fminf(m0.w, v0.w);
    m1.x = fminf(m1.x, v1.x); m1.y = fminf(m1.y, v1.y);
    m1.z = fminf(m1.z, v1.z); m1.w = fminf(m1.w, v1.w);
    m2.x = fminf(m2.x, v2.x); m2.y = fminf(m2.y, v2.y);
    m2.z = fminf(m2.z, v2.z); m2.w = fminf(m2.w, v2.w);
    m3.x = fminf(m3.x, v3.x); m3.y = fminf(m3.y, v3.y);
    m3.z = fminf(m3.z, v3.z); m3.w = fminf(m3.w, v3.w);

    // thread max via fmax tree (v_max3-friendly, short dep chain)
    const float ta = fmaxf(fmaxf(fmaxf(m0.x, m0.y), fmaxf(m0.z, m0.w)),
                           fmaxf(fmaxf(m1.x, m1.y), fmaxf(m1.z, m1.w)));
    const float tb = fmaxf(fmaxf(fmaxf(m2.x, m2.y), fmaxf(m2.z, m2.w)),
                           fmaxf(fmaxf(m3.x, m3.y), fmaxf(m3.z, m3.w)));
    const float tm = fmaxf(ta, tb);

    // lowest-k recovery (descending k; last match wins -> lowest j)
    const int j0 = tid << 4;
    int bj = 0;
    bj = (m3.w == tm) ? j0 + 15 : bj; bj = (m3.z == tm) ? j0 + 14 : bj;
    bj = (m3.y == tm) ? j0 + 13 : bj; bj = (m3.x == tm) ? j0 + 12 : bj;
    bj = (m2.w == tm) ? j0 + 11 : bj; bj = (m2.z == tm) ? j0 + 10 : bj;
    bj = (m2.y == tm) ? j0 +  9 : bj; bj = (m2.x == tm) ? j0 +  8 : bj;
    bj = (m1.w == tm) ? j0 +  7 : bj; bj = (m1.z == tm) ? j0 +  6 : bj;
    bj = (m1.y == tm) ? j0 +  5 : bj; bj = (m1.x == tm) ? j0 +  4 : bj;
    bj = (m0.w == tm) ? j0 +  3 : bj; bj = (m0.z == tm) ? j0 +  2 : bj;
    bj = (m0.y == tm) ? j0 +  1 : bj; bj = (m0.x == tm) ? j0      : bj;

    // wave winner: value DPP max, then lowest lane among holders (lane-monotone j)
    const unsigned fk   = fkey(tm);
    const unsigned wmax = wave_max_u32(fk);
    const unsigned long long mask = __ballot(fk == wmax);
    const int low = __ffsll((long long)mask) - 1;
    if (lane == low)
      atomicMax(&slot[s % 3],
                ((unsigned long long)wmax << 32) | (unsigned)(8191 - bj));
    if (tid == 0) slot[(s + 1) % 3] = 0ull;
    __syncthreads();

    const unsigned long long g = slot[s % 3];
    far = 8191 - (int)(g & 0x1FFFu);
    if (tid == 0) ob[s] = far;
  }
}

// ======================= fallback path (small ws; kept for safety) =======================

#define R64(M) \
  M(0) M(1) M(2) M(3) M(4) M(5) M(6) M(7) \
  M(8) M(9) M(10) M(11) M(12) M(13) M(14) M(15) \
  M(16) M(17) M(18) M(19) M(20) M(21) M(22) M(23) \
  M(24) M(25) M(26) M(27) M(28) M(29) M(30) M(31) \
  M(32) M(33) M(34) M(35) M(36) M(37) M(38) M(39) \
  M(40) M(41) M(42) M(43) M(44) M(45) M(46) M(47) \
  M(48) M(49) M(50) M(51) M(52) M(53) M(54) M(55) \
  M(56) M(57) M(58) M(59) M(60) M(61) M(62) M(63)

__global__ __attribute__((amdgpu_waves_per_eu(1, 2))) __launch_bounds__(TPB)
void fps_fallback(const float* __restrict__ pts, const float* __restrict__ feat,
                  int* __restrict__ out, unsigned long long* __restrict__ slots) {
  const int blk  = blockIdx.x & (NBLK - 1);
  const int b    = blockIdx.x >> 4;
  const int tid  = threadIdx.x;
  const int lane = tid & 63;
  const int p    = blk * TPB + tid;

  const float* Pp = pts  + (size_t)b * NN * 3 + (size_t)p * 3;
  const float* Fp = feat + (size_t)b * CC * NN + p;

  float fx = Pp[0], fy = Pp[1], fz = Pp[2];
#define DCF(i) float fc##i = Fp[(i) * NN];
  R64(DCF)
#undef DCF
  asm volatile("" : "+v"(fx), "+v"(fy), "+v"(fz));
#define PIN(i) asm volatile("" : "+v"(fc##i));
  R64(PIN)
#undef PIN

  float nrm = 0.f;
  nrm += fx * fx; nrm += fy * fy; nrm += fz * fz;
#define NR(i) nrm += fc##i * fc##i;
  R64(NR)
#undef NR

  __shared__ unsigned long long wred[TPB / 64];
  __shared__ int far_sh;

  if (blk == 0 && tid == 0) out[b * NPT] = 0;

  float mind = 3.0e38f;
  int far = 0;

  for (int s = 1; s < NPT; ++s) {
    const int fu = __builtin_amdgcn_readfirstlane(far);
    const float* Pq = pts  + (size_t)b * NN * 3 + (size_t)fu * 3;
    const float* Fq = feat + (size_t)b * CC * NN + fu;
    const float gx = Pq[0], gy = Pq[1], gz = Pq[2];
#define GL(i) const float gc##i = Fq[(i) * NN];
    R64(GL)
#undef GL
    float nf = 0.f, dot = 0.f;
    nf += gx * gx; nf += gy * gy; nf += gz * gz;
#define NF(i) nf += gc##i * gc##i;
    R64(NF)
#undef NF
    dot += fx * gx; dot += fy * gy; dot += fz * gz;
#define DT(i) dot += fc##i * gc##i;
    R64(DT)
#undef DT
    const float d = (nf + nrm) - 2.0f * dot;
    mind = fminf(mind, d);

    unsigned long long key =
        ((unsigned long long)fkey(mind) << 13) | (unsigned int)(8191 - p);
#pragma unroll
    for (int off = 1; off < 64; off <<= 1) {
      unsigned long long o = __shfl_xor(key, off);
      key = key > o ? key : o;
    }
    if (lane == 0) wred[tid >> 6] = key;
    __syncthreads();

    if (tid < 64) {
      unsigned long long bk = wred[0];
#pragma unroll
      for (int w = 1; w < TPB / 64; ++w) bk = bk > wred[w] ? bk : wred[w];
      unsigned long long* sb = slots + ((size_t)(s & 1) * BB + b) * NBLK;
      if (tid == 0) {
        bk |= ((unsigned long long)s << 45);
        __hip_atomic_store(&sb[blk], bk, __ATOMIC_RELAXED, __HIP_MEMORY_SCOPE_AGENT);
      }
      unsigned long long v = 0;
      for (;;) {
        if (tid < NBLK)
          v = __hip_atomic_load(&sb[tid], __ATOMIC_RELAXED, __HIP_MEMORY_SCOPE_AGENT);
        const bool ok = (tid < NBLK) ? ((v >> 45) == (unsigned long long)s) : true;
        if (__all(ok)) break;
        __builtin_amdgcn_s_sleep(1);
      }
#pragma unroll
      for (int off = 8; off; off >>= 1) {
        unsigned long long o = __shfl_xor(v, off);
        v = v > o ? v : o;
      }
      if (tid == 0) far_sh = 8191 - (int)(v & 0x1FFFu);
    }
    __syncthreads();
    far = far_sh;
    if (blk == 0 && tid == 0) out[b * NPT + s] = far;
  }
}

// ======================= host =======================

extern "C" void kernel_launch(void* const* d_in, const int* in_sizes, int n_in,
                              void* d_out, int out_size, void* d_ws, size_t ws_size,
                              hipStream_t stream) {
  const float* pts  = (const float*)d_in[0];
  const float* feat = (const float*)d_in[1];
  int* out = (int*)d_out;

  const size_t oneD = (size_t)NN * NN * sizeof(float);   // 256 MiB
  if (ws_size >= 2 * oneD) {
    float* D = (float*)d_ws;
    for (int b = 0; b < BB; ++b)
      dist_kernel<<<NT * NT, 256, 0, stream>>>(
          pts + (size_t)b * NN * 3, feat + (size_t)b * CC * NN, D + (size_t)b * NN * NN);
    scan_kernel<<<BB, 512, 0, stream>>>(D, (unsigned long long)NN * NN, out, NPT);
  } else if (ws_size >= oneD) {
    float* D = (float*)d_ws;
    for (int b = 0; b < BB; ++b) {
      dist_kernel<<<NT * NT, 256, 0, stream>>>(
          pts + (size_t)b * NN * 3, feat + (size_t)b * CC * NN, D);
      scan_kernel<<<1, 512, 0, stream>>>(D, 0, out + (size_t)b * NPT, 0);
    }
  } else {
    unsigned long long* slots = (unsigned long long*)d_ws; // [2][BB][NBLK] = 512 B
    hipMemsetAsync(d_ws, 0, 2 * BB * NBLK * sizeof(unsigned long long), stream);
    void* args[] = {(void*)&pts, (void*)&feat, (void*)&out, (void*)&slots};
    dim3 grid(BB * NBLK), block(TPB);
    hipLaunchCooperativeKernel((void*)fps_fallback, grid, block, args, 0, stream);
  }
}

// Round 15
// 2439.349 us; speedup vs baseline: 1.2165x; 1.1281x over previous
//
#include <hip/hip_runtime.h>

#define BB    2      // batches
#define NN    8192   // points per batch
#define CC    64     // extra feature channels
#define NPT   1024   // npoint
#define NT    128    // 64-wide tiles per dim (8192/64)
#define NBLK  16     // fallback: blocks per batch
#define TPB   512    // fallback: threads per block (1 point per thread)

// monotonic order-preserving key for f32 (handles negatives)
__device__ __forceinline__ unsigned int fkey(float v) {
  unsigned int u = __float_as_uint(v);
  return (u & 0x80000000u) ? ~u : (u | 0x80000000u);
}

// wave64 max-reduce of u32 via DPP (rocPRIM pattern); uniform via readlane(63).
__device__ __forceinline__ unsigned wave_max_u32(unsigned x) {
  int v = (int)x, t;
  t = __builtin_amdgcn_update_dpp(v, v, 0x111, 0xf, 0xf, false);  // row_shr:1
  v = ((unsigned)t > (unsigned)v) ? t : v;
  t = __builtin_amdgcn_update_dpp(v, v, 0x112, 0xf, 0xf, false);  // row_shr:2
  v = ((unsigned)t > (unsigned)v) ? t : v;
  t = __builtin_amdgcn_update_dpp(v, v, 0x114, 0xf, 0xf, false);  // row_shr:4
  v = ((unsigned)t > (unsigned)v) ? t : v;
  t = __builtin_amdgcn_update_dpp(v, v, 0x118, 0xf, 0xf, false);  // row_shr:8
  v = ((unsigned)t > (unsigned)v) ? t : v;
  t = __builtin_amdgcn_update_dpp(v, v, 0x142, 0xa, 0xf, false);  // row_bcast:15
  v = ((unsigned)t > (unsigned)v) ? t : v;
  t = __builtin_amdgcn_update_dpp(v, v, 0x143, 0xc, 0xf, false);  // row_bcast:31
  v = ((unsigned)t > (unsigned)v) ? t : v;
  return (unsigned)__builtin_amdgcn_readlane(v, 63);
}

// ======================= D-path: dist build (per batch) =======================
// D[i][j] = n_i + n_j - 2*dot(A_i,A_j); ascending-k fmaf chains -> D[i][i] == 0
// bit-exactly. 82% of fp32 vector peak (R9) — done.
__global__ __launch_bounds__(256) void dist_kernel(
    const float* __restrict__ Pb,    // (N,3) for this batch
    const float* __restrict__ Fb,    // (C,N) for this batch
    float* __restrict__ Db) {        // (N,N) out
  __shared__ __align__(16) float Ai[67][64];
  __shared__ __align__(16) float Aj[67][64];
  __shared__ float ni_s[64], nj_s[64];
  const int bid = blockIdx.x;
  const int bi  = bid >> 7, bj = bid & (NT - 1);
  const int t   = threadIdx.x;
  const int i0  = bi * 64, j0 = bj * 64;

  for (int idx = t; idx < 67 * 64; idx += 256) {
    const int c = idx >> 6, r = idx & 63;
    float vi, vj;
    if (c < 3) {
      vi = Pb[(size_t)(i0 + r) * 3 + c];
      vj = Pb[(size_t)(j0 + r) * 3 + c];
    } else {
      vi = Fb[(size_t)(c - 3) * NN + i0 + r];
      vj = Fb[(size_t)(c - 3) * NN + j0 + r];
    }
    Ai[c][r] = vi;
    Aj[c][r] = vj;
  }
  __syncthreads();

  if (t < 64) {
    float n = 0.f;
#pragma unroll
    for (int k = 0; k < 67; ++k) n = fmaf(Ai[k][t], Ai[k][t], n);
    ni_s[t] = n;
  } else if (t < 128) {
    const int r = t - 64;
    float n = 0.f;
#pragma unroll
    for (int k = 0; k < 67; ++k) n = fmaf(Aj[k][r], Aj[k][r], n);
    nj_s[r] = n;
  }
  __syncthreads();

  const int tx = t & 15, ty = t >> 4;
  float acc[4][4] = {};
  for (int k = 0; k < 67; ++k) {
    const float4 a = *(const float4*)&Ai[k][ty * 4];
    const float4 v = *(const float4*)&Aj[k][tx * 4];
    acc[0][0] = fmaf(a.x, v.x, acc[0][0]); acc[0][1] = fmaf(a.x, v.y, acc[0][1]);
    acc[0][2] = fmaf(a.x, v.z, acc[0][2]); acc[0][3] = fmaf(a.x, v.w, acc[0][3]);
    acc[1][0] = fmaf(a.y, v.x, acc[1][0]); acc[1][1] = fmaf(a.y, v.y, acc[1][1]);
    acc[1][2] = fmaf(a.y, v.z, acc[1][2]); acc[1][3] = fmaf(a.y, v.w, acc[1][3]);
    acc[2][0] = fmaf(a.z, v.x, acc[2][0]); acc[2][1] = fmaf(a.z, v.y, acc[2][1]);
    acc[2][2] = fmaf(a.z, v.z, acc[2][2]); acc[2][3] = fmaf(a.z, v.w, acc[2][3]);
    acc[3][0] = fmaf(a.w, v.x, acc[3][0]); acc[3][1] = fmaf(a.w, v.y, acc[3][1]);
    acc[3][2] = fmaf(a.w, v.z, acc[3][2]); acc[3][3] = fmaf(a.w, v.w, acc[3][3]);
  }

  const float4 nj4 = *(const float4*)&nj_s[tx * 4];
#pragma unroll
  for (int r = 0; r < 4; ++r) {
    const float nir = ni_s[ty * 4 + r];
    float4 w;
    w.x = (nir + nj4.x) - 2.0f * acc[r][0];
    w.y = (nir + nj4.y) - 2.0f * acc[r][1];
    w.z = (nir + nj4.z) - 2.0f * acc[r][2];
    w.w = (nir + nj4.w) - 2.0f * acc[r][3];
    *(float4*)&Db[(size_t)(i0 + ty * 4 + r) * NN + j0 + tx * 4] = w;
  }
}

// ======================= D-path: serial scan (R9 structure + fmax tree) ======
// One block (512 thr, 8 waves, 1 CU) per batch; block-local sync only.
// Loads: R9's strided mapping row4[tid + 512k] — each instruction is a dense
// 1KB/wave access (R14's contiguous-per-thread mapping cost 30%: 64B lane
// stride = 4x the memory transactions).
// Per-thread argmax: fmax tree (depth 4) + ONE fkey + descending select
// ladder (lowest j wins) — replaces R9's 16x u64-key chain (~130 VALU insts
// -> ~64). Wave reduce: value DPP chain, then tie DPP chain on (8191-bj)
// among value-winners. 3-slot rotating LDS cell + single barrier (R9-proven).
__global__ __launch_bounds__(512) void scan_kernel(
    const float* __restrict__ D, unsigned long long dstride,
    int* __restrict__ out, int ostride) {
  const int b = blockIdx.x;
  const float* Db = D + (size_t)b * dstride;
  int* ob = out + (size_t)b * ostride;
  const int tid = threadIdx.x, lane = tid & 63;
  __shared__ unsigned long long slot[3];
  if (tid < 3) slot[tid] = 0ull;
  __syncthreads();

  float4 m0 = make_float4(3.0e38f, 3.0e38f, 3.0e38f, 3.0e38f);
  float4 m1 = m0, m2 = m0, m3 = m0;

  if (tid == 0) ob[0] = 0;
  int far = 0;

  for (int s = 1; s < NPT; ++s) {
    // strided row load: 4 dense 1KB/wave instructions
    const float4* row4 = (const float4*)(Db + (size_t)far * NN);
    const float4 v0 = row4[tid];
    const float4 v1 = row4[tid + 512];
    const float4 v2 = row4[tid + 1024];
    const float4 v3 = row4[tid + 1536];
    m0.x = fminf(m0.x, v0.x); m0.y = fminf(m0.y, v0.y);
    m0.z = fminf(m0.z, v0.z); m0.w = fminf(m0.w, v0.w);
    m1.x = fminf(m1.x, v1.x); m1.y = fminf(m1.y, v1.y);
    m1.z = fminf(m1.z, v1.z); m1.w = fminf(m1.w, v1.w);
    m2.x = fminf(m2.x, v2.x); m2.y = fminf(m2.y, v2.y);
    m2.z = fminf(m2.z, v2.z); m2.w = fminf(m2.w, v2.w);
    m3.x = fminf(m3.x, v3.x); m3.y = fminf(m3.y, v3.y);
    m3.z = fminf(m3.z, v3.z); m3.w = fminf(m3.w, v3.w);

    // thread max via fmax tree (v_max3-friendly, short dep chain)
    const float ta = fmaxf(fmaxf(fmaxf(m0.x, m0.y), fmaxf(m0.z, m0.w)),
                           fmaxf(fmaxf(m1.x, m1.y), fmaxf(m1.z, m1.w)));
    const float tb = fmaxf(fmaxf(fmaxf(m2.x, m2.y), fmaxf(m2.z, m2.w)),
                           fmaxf(fmaxf(m3.x, m3.y), fmaxf(m3.z, m3.w)));
    const float tm = fmaxf(ta, tb);

    // lowest-j recovery: descending j; last match wins -> lowest j
    const int j0 = tid * 4;
    int bj = 0;
    bj = (m3.w == tm) ? j0 + 6147 : bj; bj = (m3.z == tm) ? j0 + 6146 : bj;
    bj = (m3.y == tm) ? j0 + 6145 : bj; bj = (m3.x == tm) ? j0 + 6144 : bj;
    bj = (m2.w == tm) ? j0 + 4099 : bj; bj = (m2.z == tm) ? j0 + 4098 : bj;
    bj = (m2.y == tm) ? j0 + 4097 : bj; bj = (m2.x == tm) ? j0 + 4096 : bj;
    bj = (m1.w == tm) ? j0 + 2051 : bj; bj = (m1.z == tm) ? j0 + 2050 : bj;
    bj = (m1.y == tm) ? j0 + 2049 : bj; bj = (m1.x == tm) ? j0 + 2048 : bj;
    bj = (m0.w == tm) ? j0 + 3 : bj;    bj = (m0.z == tm) ? j0 + 2 : bj;
    bj = (m0.y == tm) ? j0 + 1 : bj;    bj = (m0.x == tm) ? j0 : bj;

    // wave reduce: value first, then lowest-j among value winners
    const unsigned fk   = fkey(tm);
    const unsigned wmax = wave_max_u32(fk);
    const unsigned cand = (fk == wmax) ? (8191u - (unsigned)bj) : 0u;
    const unsigned wtie = wave_max_u32(cand);

    // one LDS atomic per wave into rotating slot; reset next slot this window
    if (lane == 0)
      atomicMax(&slot[s % 3], ((unsigned long long)wmax << 32) | wtie);
    if (tid == 0) slot[(s + 1) % 3] = 0ull;
    __syncthreads();

    const unsigned long long g = slot[s % 3];
    far = 8191 - (int)(g & 0x1FFFu);
    if (tid == 0) ob[s] = far;
  }
}

// ======================= fallback path (small ws; kept for safety) =======================

#define R64(M) \
  M(0) M(1) M(2) M(3) M(4) M(5) M(6) M(7) \
  M(8) M(9) M(10) M(11) M(12) M(13) M(14) M(15) \
  M(16) M(17) M(18) M(19) M(20) M(21) M(22) M(23) \
  M(24) M(25) M(26) M(27) M(28) M(29) M(30) M(31) \
  M(32) M(33) M(34) M(35) M(36) M(37) M(38) M(39) \
  M(40) M(41) M(42) M(43) M(44) M(45) M(46) M(47) \
  M(48) M(49) M(50) M(51) M(52) M(53) M(54) M(55) \
  M(56) M(57) M(58) M(59) M(60) M(61) M(62) M(63)

__global__ __attribute__((amdgpu_waves_per_eu(1, 2))) __launch_bounds__(TPB)
void fps_fallback(const float* __restrict__ pts, const float* __restrict__ feat,
                  int* __restrict__ out, unsigned long long* __restrict__ slots) {
  const int blk  = blockIdx.x & (NBLK - 1);
  const int b    = blockIdx.x >> 4;
  const int tid  = threadIdx.x;
  const int lane = tid & 63;
  const int p    = blk * TPB + tid;

  const float* Pp = pts  + (size_t)b * NN * 3 + (size_t)p * 3;
  const float* Fp = feat + (size_t)b * CC * NN + p;

  float fx = Pp[0], fy = Pp[1], fz = Pp[2];
#define DCF(i) float fc##i = Fp[(i) * NN];
  R64(DCF)
#undef DCF
  asm volatile("" : "+v"(fx), "+v"(fy), "+v"(fz));
#define PIN(i) asm volatile("" : "+v"(fc##i));
  R64(PIN)
#undef PIN

  float nrm = 0.f;
  nrm += fx * fx; nrm += fy * fy; nrm += fz * fz;
#define NR(i) nrm += fc##i * fc##i;
  R64(NR)
#undef NR

  __shared__ unsigned long long wred[TPB / 64];
  __shared__ int far_sh;

  if (blk == 0 && tid == 0) out[b * NPT] = 0;

  float mind = 3.0e38f;
  int far = 0;

  for (int s = 1; s < NPT; ++s) {
    const int fu = __builtin_amdgcn_readfirstlane(far);
    const float* Pq = pts  + (size_t)b * NN * 3 + (size_t)fu * 3;
    const float* Fq = feat + (size_t)b * CC * NN + fu;
    const float gx = Pq[0], gy = Pq[1], gz = Pq[2];
#define GL(i) const float gc##i = Fq[(i) * NN];
    R64(GL)
#undef GL
    float nf = 0.f, dot = 0.f;
    nf += gx * gx; nf += gy * gy; nf += gz * gz;
#define NF(i) nf += gc##i * gc##i;
    R64(NF)
#undef NF
    dot += fx * gx; dot += fy * gy; dot += fz * gz;
#define DT(i) dot += fc##i * gc##i;
    R64(DT)
#undef DT
    const float d = (nf + nrm) - 2.0f * dot;
    mind = fminf(mind, d);

    unsigned long long key =
        ((unsigned long long)fkey(mind) << 13) | (unsigned int)(8191 - p);
#pragma unroll
    for (int off = 1; off < 64; off <<= 1) {
      unsigned long long o = __shfl_xor(key, off);
      key = key > o ? key : o;
    }
    if (lane == 0) wred[tid >> 6] = key;
    __syncthreads();

    if (tid < 64) {
      unsigned long long bk = wred[0];
#pragma unroll
      for (int w = 1; w < TPB / 64; ++w) bk = bk > wred[w] ? bk : wred[w];
      unsigned long long* sb = slots + ((size_t)(s & 1) * BB + b) * NBLK;
      if (tid == 0) {
        bk |= ((unsigned long long)s << 45);
        __hip_atomic_store(&sb[blk], bk, __ATOMIC_RELAXED, __HIP_MEMORY_SCOPE_AGENT);
      }
      unsigned long long v = 0;
      for (;;) {
        if (tid < NBLK)
          v = __hip_atomic_load(&sb[tid], __ATOMIC_RELAXED, __HIP_MEMORY_SCOPE_AGENT);
        const bool ok = (tid < NBLK) ? ((v >> 45) == (unsigned long long)s) : true;
        if (__all(ok)) break;
        __builtin_amdgcn_s_sleep(1);
      }
#pragma unroll
      for (int off = 8; off; off >>= 1) {
        unsigned long long o = __shfl_xor(v, off);
        v = v > o ? v : o;
      }
      if (tid == 0) far_sh = 8191 - (int)(v & 0x1FFFu);
    }
    __syncthreads();
    far = far_sh;
    if (blk == 0 && tid == 0) out[b * NPT + s] = far;
  }
}

// ======================= host =======================

extern "C" void kernel_launch(void* const* d_in, const int* in_sizes, int n_in,
                              void* d_out, int out_size, void* d_ws, size_t ws_size,
                              hipStream_t stream) {
  const float* pts  = (const float*)d_in[0];
  const float* feat = (const float*)d_in[1];
  int* out = (int*)d_out;

  const size_t oneD = (size_t)NN * NN * sizeof(float);   // 256 MiB
  if (ws_size >= 2 * oneD) {
    float* D = (float*)d_ws;
    for (int b = 0; b < BB; ++b)
      dist_kernel<<<NT * NT, 256, 0, stream>>>(
          pts + (size_t)b * NN * 3, feat + (size_t)b * CC * NN, D + (size_t)b * NN * NN);
    scan_kernel<<<BB, 512, 0, stream>>>(D, (unsigned long long)NN * NN, out, NPT);
  } else if (ws_size >= oneD) {
    float* D = (float*)d_ws;
    for (int b = 0; b < BB; ++b) {
      dist_kernel<<<NT * NT, 256, 0, stream>>>(
          pts + (size_t)b * NN * 3, feat + (size_t)b * CC * NN, D);
      scan_kernel<<<1, 512, 0, stream>>>(D, 0, out + (size_t)b * NPT, 0);
    }
  } else {
    unsigned long long* slots = (unsigned long long*)d_ws; // [2][BB][NBLK] = 512 B
    hipMemsetAsync(d_ws, 0, 2 * BB * NBLK * sizeof(unsigned long long), stream);
    void* args[] = {(void*)&pts, (void*)&feat, (void*)&out, (void*)&slots};
    dim3 grid(BB * NBLK), block(TPB);
    hipLaunchCooperativeKernel((void*)fps_fallback, grid, block, args, 0, stream);
  }
}

// Round 16
// 2216.339 us; speedup vs baseline: 1.3389x; 1.1006x over previous
//
#include <hip/hip_runtime.h>

#define BB    2      // batches
#define NN    8192   // points per batch
#define CC    64     // extra feature channels
#define NPT   1024   // npoint
#define NT    128    // 64-wide tiles per dim (8192/64)
#define NBLK  16     // fallback: blocks per batch
#define TPB   512    // fallback: threads per block (1 point per thread)

// monotonic order-preserving key for f32 (handles negatives)
__device__ __forceinline__ unsigned int fkey(float v) {
  unsigned int u = __float_as_uint(v);
  return (u & 0x80000000u) ? ~u : (u | 0x80000000u);
}

// wave64 max-reduce of u32 via DPP (rocPRIM pattern); uniform via readlane(63).
__device__ __forceinline__ unsigned wave_max_u32(unsigned x) {
  int v = (int)x, t;
  t = __builtin_amdgcn_update_dpp(v, v, 0x111, 0xf, 0xf, false);  // row_shr:1
  v = ((unsigned)t > (unsigned)v) ? t : v;
  t = __builtin_amdgcn_update_dpp(v, v, 0x112, 0xf, 0xf, false);  // row_shr:2
  v = ((unsigned)t > (unsigned)v) ? t : v;
  t = __builtin_amdgcn_update_dpp(v, v, 0x114, 0xf, 0xf, false);  // row_shr:4
  v = ((unsigned)t > (unsigned)v) ? t : v;
  t = __builtin_amdgcn_update_dpp(v, v, 0x118, 0xf, 0xf, false);  // row_shr:8
  v = ((unsigned)t > (unsigned)v) ? t : v;
  t = __builtin_amdgcn_update_dpp(v, v, 0x142, 0xa, 0xf, false);  // row_bcast:15
  v = ((unsigned)t > (unsigned)v) ? t : v;
  t = __builtin_amdgcn_update_dpp(v, v, 0x143, 0xc, 0xf, false);  // row_bcast:31
  v = ((unsigned)t > (unsigned)v) ? t : v;
  return (unsigned)__builtin_amdgcn_readlane(v, 63);
}

// ======================= D-path: dist build (per batch) =======================
// D[i][j] = n_i + n_j - 2*dot(A_i,A_j); ascending-k fmaf chains -> D[i][i] == 0
// bit-exactly. 82% of fp32 vector peak (R9) — done.
__global__ __launch_bounds__(256) void dist_kernel(
    const float* __restrict__ Pb,    // (N,3) for this batch
    const float* __restrict__ Fb,    // (C,N) for this batch
    float* __restrict__ Db) {        // (N,N) out
  __shared__ __align__(16) float Ai[67][64];
  __shared__ __align__(16) float Aj[67][64];
  __shared__ float ni_s[64], nj_s[64];
  const int bid = blockIdx.x;
  const int bi  = bid >> 7, bj = bid & (NT - 1);
  const int t   = threadIdx.x;
  const int i0  = bi * 64, j0 = bj * 64;

  for (int idx = t; idx < 67 * 64; idx += 256) {
    const int c = idx >> 6, r = idx & 63;
    float vi, vj;
    if (c < 3) {
      vi = Pb[(size_t)(i0 + r) * 3 + c];
      vj = Pb[(size_t)(j0 + r) * 3 + c];
    } else {
      vi = Fb[(size_t)(c - 3) * NN + i0 + r];
      vj = Fb[(size_t)(c - 3) * NN + j0 + r];
    }
    Ai[c][r] = vi;
    Aj[c][r] = vj;
  }
  __syncthreads();

  if (t < 64) {
    float n = 0.f;
#pragma unroll
    for (int k = 0; k < 67; ++k) n = fmaf(Ai[k][t], Ai[k][t], n);
    ni_s[t] = n;
  } else if (t < 128) {
    const int r = t - 64;
    float n = 0.f;
#pragma unroll
    for (int k = 0; k < 67; ++k) n = fmaf(Aj[k][r], Aj[k][r], n);
    nj_s[r] = n;
  }
  __syncthreads();

  const int tx = t & 15, ty = t >> 4;
  float acc[4][4] = {};
  for (int k = 0; k < 67; ++k) {
    const float4 a = *(const float4*)&Ai[k][ty * 4];
    const float4 v = *(const float4*)&Aj[k][tx * 4];
    acc[0][0] = fmaf(a.x, v.x, acc[0][0]); acc[0][1] = fmaf(a.x, v.y, acc[0][1]);
    acc[0][2] = fmaf(a.x, v.z, acc[0][2]); acc[0][3] = fmaf(a.x, v.w, acc[0][3]);
    acc[1][0] = fmaf(a.y, v.x, acc[1][0]); acc[1][1] = fmaf(a.y, v.y, acc[1][1]);
    acc[1][2] = fmaf(a.y, v.z, acc[1][2]); acc[1][3] = fmaf(a.y, v.w, acc[1][3]);
    acc[2][0] = fmaf(a.z, v.x, acc[2][0]); acc[2][1] = fmaf(a.z, v.y, acc[2][1]);
    acc[2][2] = fmaf(a.z, v.z, acc[2][2]); acc[2][3] = fmaf(a.z, v.w, acc[2][3]);
    acc[3][0] = fmaf(a.w, v.x, acc[3][0]); acc[3][1] = fmaf(a.w, v.y, acc[3][1]);
    acc[3][2] = fmaf(a.w, v.z, acc[3][2]); acc[3][3] = fmaf(a.w, v.w, acc[3][3]);
  }

  const float4 nj4 = *(const float4*)&nj_s[tx * 4];
#pragma unroll
  for (int r = 0; r < 4; ++r) {
    const float nir = ni_s[ty * 4 + r];
    float4 w;
    w.x = (nir + nj4.x) - 2.0f * acc[r][0];
    w.y = (nir + nj4.y) - 2.0f * acc[r][1];
    w.z = (nir + nj4.z) - 2.0f * acc[r][2];
    w.w = (nir + nj4.w) - 2.0f * acc[r][3];
    *(float4*)&Db[(size_t)(i0 + ty * 4 + r) * NN + j0 + tx * 4] = w;
  }
}

// ======================= D-path: serial scan (R9-exact + LDS out staging) ====
// One block (512 thr, 8 waves, 1 CU) per batch; block-local sync only.
// R9's 956us body verbatim (strided loads, u64-key chain, dual DPP reduce,
// 3-slot rotating atomicMax, single barrier) with ONE change: the in-loop
// global store ob[s] is replaced by an LDS write. __syncthreads emits
// s_waitcnt vmcnt(0) before s_barrier; with a global store in flight that
// means a store-ack round trip (~400-900cy) on the serial chain EVERY step.
// LDS writes drain via lgkmcnt (~20cy). Results flushed coalesced at the end.
__global__ __launch_bounds__(512) void scan_kernel(
    const float* __restrict__ D, unsigned long long dstride,
    int* __restrict__ out, int ostride) {
  const int b = blockIdx.x;
  const float* Db = D + (size_t)b * dstride;
  int* ob = out + (size_t)b * ostride;
  const int tid = threadIdx.x, lane = tid & 63;
  __shared__ unsigned long long slot[3];
  __shared__ int out_lds[NPT];
  if (tid < 3) slot[tid] = 0ull;
  if (tid == 0) out_lds[0] = 0;
  __syncthreads();

  float4 m[4];
#pragma unroll
  for (int k = 0; k < 4; ++k) m[k] = make_float4(3.0e38f, 3.0e38f, 3.0e38f, 3.0e38f);

  int far = 0;

  for (int s = 1; s < NPT; ++s) {
    const float4* row4 = (const float4*)(Db + (size_t)far * NN);
    float4 v[4];
#pragma unroll
    for (int k = 0; k < 4; ++k) v[k] = row4[tid + 512 * k];
#pragma unroll
    for (int k = 0; k < 4; ++k) {
      m[k].x = fminf(m[k].x, v[k].x);
      m[k].y = fminf(m[k].y, v[k].y);
      m[k].z = fminf(m[k].z, v[k].z);
      m[k].w = fminf(m[k].w, v[k].w);
    }

    // per-thread argmax, strict > over ascending j -> lowest-index tie-break
    const int j0 = tid * 4;
    float best = m[0].x; int bj = j0;
#define CHK(val, jj) if ((val) > best) { best = (val); bj = (jj); }
    CHK(m[0].y, j0 + 1) CHK(m[0].z, j0 + 2) CHK(m[0].w, j0 + 3)
    CHK(m[1].x, j0 + 2048) CHK(m[1].y, j0 + 2049) CHK(m[1].z, j0 + 2050) CHK(m[1].w, j0 + 2051)
    CHK(m[2].x, j0 + 4096) CHK(m[2].y, j0 + 4097) CHK(m[2].z, j0 + 4098) CHK(m[2].w, j0 + 4099)
    CHK(m[3].x, j0 + 6144) CHK(m[3].y, j0 + 6145) CHK(m[3].z, j0 + 6146) CHK(m[3].w, j0 + 6147)
#undef CHK

    // wave reduce: value first, then lowest-j among value winners
    const unsigned fk   = fkey(best);
    const unsigned wmax = wave_max_u32(fk);
    const unsigned cand = (fk == wmax) ? (8191u - (unsigned)bj) : 0u;
    const unsigned wtie = wave_max_u32(cand);

    // one LDS atomic per wave; rotate slots mod 3; reset next slot this window
    if (lane == 0)
      atomicMax(&slot[s % 3], ((unsigned long long)wmax << 32) | wtie);
    if (tid == 0) slot[(s + 1) % 3] = 0ull;
    __syncthreads();

    const unsigned long long g = slot[s % 3];
    far = 8191 - (int)(g & 0x1FFFu);
    if (tid == 0) out_lds[s] = far;   // LDS write: no vmem on the barrier path
  }

  // coalesced final flush (2 ints per thread)
  __syncthreads();
#pragma unroll
  for (int i = tid; i < NPT; i += 512) ob[i] = out_lds[i];
}

// ======================= fallback path (small ws; kept for safety) =======================

#define R64(M) \
  M(0) M(1) M(2) M(3) M(4) M(5) M(6) M(7) \
  M(8) M(9) M(10) M(11) M(12) M(13) M(14) M(15) \
  M(16) M(17) M(18) M(19) M(20) M(21) M(22) M(23) \
  M(24) M(25) M(26) M(27) M(28) M(29) M(30) M(31) \
  M(32) M(33) M(34) M(35) M(36) M(37) M(38) M(39) \
  M(40) M(41) M(42) M(43) M(44) M(45) M(46) M(47) \
  M(48) M(49) M(50) M(51) M(52) M(53) M(54) M(55) \
  M(56) M(57) M(58) M(59) M(60) M(61) M(62) M(63)

__global__ __attribute__((amdgpu_waves_per_eu(1, 2))) __launch_bounds__(TPB)
void fps_fallback(const float* __restrict__ pts, const float* __restrict__ feat,
                  int* __restrict__ out, unsigned long long* __restrict__ slots) {
  const int blk  = blockIdx.x & (NBLK - 1);
  const int b    = blockIdx.x >> 4;
  const int tid  = threadIdx.x;
  const int lane = tid & 63;
  const int p    = blk * TPB + tid;

  const float* Pp = pts  + (size_t)b * NN * 3 + (size_t)p * 3;
  const float* Fp = feat + (size_t)b * CC * NN + p;

  float fx = Pp[0], fy = Pp[1], fz = Pp[2];
#define DCF(i) float fc##i = Fp[(i) * NN];
  R64(DCF)
#undef DCF
  asm volatile("" : "+v"(fx), "+v"(fy), "+v"(fz));
#define PIN(i) asm volatile("" : "+v"(fc##i));
  R64(PIN)
#undef PIN

  float nrm = 0.f;
  nrm += fx * fx; nrm += fy * fy; nrm += fz * fz;
#define NR(i) nrm += fc##i * fc##i;
  R64(NR)
#undef NR

  __shared__ unsigned long long wred[TPB / 64];
  __shared__ int far_sh;

  if (blk == 0 && tid == 0) out[b * NPT] = 0;

  float mind = 3.0e38f;
  int far = 0;

  for (int s = 1; s < NPT; ++s) {
    const int fu = __builtin_amdgcn_readfirstlane(far);
    const float* Pq = pts  + (size_t)b * NN * 3 + (size_t)fu * 3;
    const float* Fq = feat + (size_t)b * CC * NN + fu;
    const float gx = Pq[0], gy = Pq[1], gz = Pq[2];
#define GL(i) const float gc##i = Fq[(i) * NN];
    R64(GL)
#undef GL
    float nf = 0.f, dot = 0.f;
    nf += gx * gx; nf += gy * gy; nf += gz * gz;
#define NF(i) nf += gc##i * gc##i;
    R64(NF)
#undef NF
    dot += fx * gx; dot += fy * gy; dot += fz * gz;
#define DT(i) dot += fc##i * gc##i;
    R64(DT)
#undef DT
    const float d = (nf + nrm) - 2.0f * dot;
    mind = fminf(mind, d);

    unsigned long long key =
        ((unsigned long long)fkey(mind) << 13) | (unsigned int)(8191 - p);
#pragma unroll
    for (int off = 1; off < 64; off <<= 1) {
      unsigned long long o = __shfl_xor(key, off);
      key = key > o ? key : o;
    }
    if (lane == 0) wred[tid >> 6] = key;
    __syncthreads();

    if (tid < 64) {
      unsigned long long bk = wred[0];
#pragma unroll
      for (int w = 1; w < TPB / 64; ++w) bk = bk > wred[w] ? bk : wred[w];
      unsigned long long* sb = slots + ((size_t)(s & 1) * BB + b) * NBLK;
      if (tid == 0) {
        bk |= ((unsigned long long)s << 45);
        __hip_atomic_store(&sb[blk], bk, __ATOMIC_RELAXED, __HIP_MEMORY_SCOPE_AGENT);
      }
      unsigned long long v = 0;
      for (;;) {
        if (tid < NBLK)
          v = __hip_atomic_load(&sb[tid], __ATOMIC_RELAXED, __HIP_MEMORY_SCOPE_AGENT);
        const bool ok = (tid < NBLK) ? ((v >> 45) == (unsigned long long)s) : true;
        if (__all(ok)) break;
        __builtin_amdgcn_s_sleep(1);
      }
#pragma unroll
      for (int off = 8; off; off >>= 1) {
        unsigned long long o = __shfl_xor(v, off);
        v = v > o ? v : o;
      }
      if (tid == 0) far_sh = 8191 - (int)(v & 0x1FFFu);
    }
    __syncthreads();
    far = far_sh;
    if (blk == 0 && tid == 0) out[b * NPT + s] = far;
  }
}

// ======================= host =======================

extern "C" void kernel_launch(void* const* d_in, const int* in_sizes, int n_in,
                              void* d_out, int out_size, void* d_ws, size_t ws_size,
                              hipStream_t stream) {
  const float* pts  = (const float*)d_in[0];
  const float* feat = (const float*)d_in[1];
  int* out = (int*)d_out;

  const size_t oneD = (size_t)NN * NN * sizeof(float);   // 256 MiB
  if (ws_size >= 2 * oneD) {
    float* D = (float*)d_ws;
    for (int b = 0; b < BB; ++b)
      dist_kernel<<<NT * NT, 256, 0, stream>>>(
          pts + (size_t)b * NN * 3, feat + (size_t)b * CC * NN, D + (size_t)b * NN * NN);
    scan_kernel<<<BB, 512, 0, stream>>>(D, (unsigned long long)NN * NN, out, NPT);
  } else if (ws_size >= oneD) {
    float* D = (float*)d_ws;
    for (int b = 0; b < BB; ++b) {
      dist_kernel<<<NT * NT, 256, 0, stream>>>(
          pts + (size_t)b * NN * 3, feat + (size_t)b * CC * NN, D);
      scan_kernel<<<1, 512, 0, stream>>>(D, 0, out + (size_t)b * NPT, 0);
    }
  } else {
    unsigned long long* slots = (unsigned long long*)d_ws; // [2][BB][NBLK] = 512 B
    hipMemsetAsync(d_ws, 0, 2 * BB * NBLK * sizeof(unsigned long long), stream);
    void* args[] = {(void*)&pts, (void*)&feat, (void*)&out, (void*)&slots};
    dim3 grid(BB * NBLK), block(TPB);
    hipLaunchCooperativeKernel((void*)fps_fallback, grid, block, args, 0, stream);
  }
}